// Round 1
// baseline (126.245 us; speedup 1.0000x reference)
//
#include <hip/hip_runtime.h>
#include <math.h>

#define NRES 1024
#define TM_EPS 1e-8f

// ---------------- Kernel 1: per-batch sums ----------------
// acc layout: [0..2] sum(pred), [3..5] sum(actual), [6..14] S[i][j] = sum actual_i * pred_j
__global__ void tm_reduce1(const float* __restrict__ pred, const float* __restrict__ act,
                           float* __restrict__ sums) {
    int b = blockIdx.x;
    const float4* p4 = (const float4*)(pred + (size_t)b * NRES * 3);
    const float4* a4 = (const float4*)(act  + (size_t)b * NRES * 3);
    int t = threadIdx.x;

    float4 pf0 = p4[3 * t + 0], pf1 = p4[3 * t + 1], pf2 = p4[3 * t + 2];
    float4 af0 = a4[3 * t + 0], af1 = a4[3 * t + 1], af2 = a4[3 * t + 2];

    float px[4] = {pf0.x, pf0.w, pf1.z, pf2.y};
    float py[4] = {pf0.y, pf1.x, pf1.w, pf2.z};
    float pz[4] = {pf0.z, pf1.y, pf2.x, pf2.w};
    float ax[4] = {af0.x, af0.w, af1.z, af2.y};
    float ay[4] = {af0.y, af1.x, af1.w, af2.z};
    float az[4] = {af0.z, af1.y, af2.x, af2.w};

    float acc[15];
#pragma unroll
    for (int i = 0; i < 15; i++) acc[i] = 0.f;
#pragma unroll
    for (int r = 0; r < 4; r++) {
        acc[0] += px[r]; acc[1] += py[r]; acc[2] += pz[r];
        acc[3] += ax[r]; acc[4] += ay[r]; acc[5] += az[r];
        acc[6]  += ax[r] * px[r]; acc[7]  += ax[r] * py[r]; acc[8]  += ax[r] * pz[r];
        acc[9]  += ay[r] * px[r]; acc[10] += ay[r] * py[r]; acc[11] += ay[r] * pz[r];
        acc[12] += az[r] * px[r]; acc[13] += az[r] * py[r]; acc[14] += az[r] * pz[r];
    }

    // wave(64) shuffle reduction
#pragma unroll
    for (int off = 32; off > 0; off >>= 1) {
#pragma unroll
        for (int i = 0; i < 15; i++) acc[i] += __shfl_down(acc[i], off);
    }
    __shared__ float red[4][15];
    int wave = threadIdx.x >> 6, lane = threadIdx.x & 63;
    if (lane == 0) {
#pragma unroll
        for (int i = 0; i < 15; i++) red[wave][i] = acc[i];
    }
    __syncthreads();
    if (threadIdx.x < 15) {
        int i = threadIdx.x;
        sums[(size_t)b * 16 + i] = red[0][i] + red[1][i] + red[2][i] + red[3][i];
    }
}

// ---------------- Kernel 2: per-batch Kabsch rotation via Horn quaternion ----------------
__global__ void tm_kabsch(const float* __restrict__ sums, float* __restrict__ rot, int B) {
    int b = blockIdx.x * blockDim.x + threadIdx.x;
    if (b >= B) return;
    const float* s = sums + (size_t)b * 16;
    const double n = (double)NRES;
    double mp[3], mq[3];
#pragma unroll
    for (int i = 0; i < 3; i++) { mp[i] = (double)s[i] / n; mq[i] = (double)s[3 + i] / n; }
    double M[3][3];
#pragma unroll
    for (int i = 0; i < 3; i++)
#pragma unroll
        for (int j = 0; j < 3; j++)
            M[i][j] = (double)s[6 + i * 3 + j] - n * mq[i] * mp[j];

    // Horn's 4x4 key matrix. S_ab = sum q_a p_b = M[a][b] (set1=actual/q -> set2=pred/p)
    double Sxx = M[0][0], Sxy = M[0][1], Sxz = M[0][2];
    double Syx = M[1][0], Syy = M[1][1], Syz = M[1][2];
    double Szx = M[2][0], Szy = M[2][1], Szz = M[2][2];
    double a[4][4];
    a[0][0] = Sxx + Syy + Szz; a[0][1] = Syz - Szy;        a[0][2] = Szx - Sxz;         a[0][3] = Sxy - Syx;
    a[1][0] = a[0][1];         a[1][1] = Sxx - Syy - Szz;  a[1][2] = Sxy + Syx;         a[1][3] = Szx + Sxz;
    a[2][0] = a[0][2];         a[2][1] = a[1][2];          a[2][2] = -Sxx + Syy - Szz;  a[2][3] = Syz + Szy;
    a[3][0] = a[0][3];         a[3][1] = a[1][3];          a[3][2] = a[2][3];           a[3][3] = -Sxx - Syy + Szz;

    // cyclic Jacobi eigen-decomposition (double)
    double v[4][4];
#pragma unroll
    for (int i = 0; i < 4; i++)
#pragma unroll
        for (int j = 0; j < 4; j++) v[i][j] = (i == j) ? 1.0 : 0.0;

    double fro = 0.0;
    for (int i = 0; i < 4; i++) for (int j = 0; j < 4; j++) fro += a[i][j] * a[i][j];
    fro = sqrt(fro) + 1e-300;

    for (int sweep = 0; sweep < 25; sweep++) {
        double off = 0.0;
        for (int p = 0; p < 3; p++) for (int q = p + 1; q < 4; q++) off += a[p][q] * a[p][q];
        if (off < 1e-26 * fro * fro) break;
        for (int p = 0; p < 3; p++) {
            for (int q = p + 1; q < 4; q++) {
                double apq = a[p][q];
                if (fabs(apq) < 1e-30 * fro) continue;
                double theta = (a[q][q] - a[p][p]) / (2.0 * apq);
                double tt = (theta >= 0.0 ? 1.0 : -1.0) / (fabs(theta) + sqrt(theta * theta + 1.0));
                double c = 1.0 / sqrt(tt * tt + 1.0), sv = tt * c;
                for (int k = 0; k < 4; k++) {
                    double akp = a[k][p], akq = a[k][q];
                    a[k][p] = c * akp - sv * akq;
                    a[k][q] = sv * akp + c * akq;
                }
                for (int k = 0; k < 4; k++) {
                    double apk = a[p][k], aqk = a[q][k];
                    a[p][k] = c * apk - sv * aqk;
                    a[q][k] = sv * apk + c * aqk;
                }
                for (int k = 0; k < 4; k++) {
                    double vkp = v[k][p], vkq = v[k][q];
                    v[k][p] = c * vkp - sv * vkq;
                    v[k][q] = sv * vkp + c * vkq;
                }
            }
        }
    }

    int best = 0;
    double bestval = a[0][0];
    for (int i = 1; i < 4; i++) if (a[i][i] > bestval) { bestval = a[i][i]; best = i; }
    double w = v[0][best], x = v[1][best], y = v[2][best], z = v[3][best];
    double nrm = sqrt(w * w + x * x + y * y + z * z);
    w /= nrm; x /= nrm; y /= nrm; z /= nrm;

    // rotation A (columns): A * q_col ~= p_col
    double A[3][3];
    A[0][0] = 1.0 - 2.0 * (y * y + z * z); A[0][1] = 2.0 * (x * y - w * z);       A[0][2] = 2.0 * (x * z + w * y);
    A[1][0] = 2.0 * (x * y + w * z);       A[1][1] = 1.0 - 2.0 * (x * x + z * z); A[1][2] = 2.0 * (y * z - w * x);
    A[2][0] = 2.0 * (x * z - w * y);       A[2][1] = 2.0 * (y * z + w * x);       A[2][2] = 1.0 - 2.0 * (x * x + y * y);

    float* o = rot + (size_t)b * 12;
#pragma unroll
    for (int i = 0; i < 3; i++)
#pragma unroll
        for (int j = 0; j < 3; j++) o[i * 3 + j] = (float)A[i][j];
    // t = mu_p - A * mu_q
#pragma unroll
    for (int i = 0; i < 3; i++)
        o[9 + i] = (float)(mp[i] - (A[i][0] * mq[0] + A[i][1] * mq[1] + A[i][2] * mq[2]));
}

// ---------------- Kernel 3: deviations + TM-score sum ----------------
__global__ void tm_score(const float* __restrict__ pred, const float* __restrict__ act,
                         const float* __restrict__ rot, float* __restrict__ out,
                         float scale, float inv_d02) {
    int b = blockIdx.x;
    const float* R = rot + (size_t)b * 12;
    float A00 = R[0], A01 = R[1], A02 = R[2];
    float A10 = R[3], A11 = R[4], A12 = R[5];
    float A20 = R[6], A21 = R[7], A22 = R[8];
    float t0 = R[9], t1 = R[10], t2 = R[11];

    const float4* p4 = (const float4*)(pred + (size_t)b * NRES * 3);
    const float4* a4 = (const float4*)(act  + (size_t)b * NRES * 3);
    int t = threadIdx.x;
    float4 pf0 = p4[3 * t + 0], pf1 = p4[3 * t + 1], pf2 = p4[3 * t + 2];
    float4 af0 = a4[3 * t + 0], af1 = a4[3 * t + 1], af2 = a4[3 * t + 2];

    float px[4] = {pf0.x, pf0.w, pf1.z, pf2.y};
    float py[4] = {pf0.y, pf1.x, pf1.w, pf2.z};
    float pz[4] = {pf0.z, pf1.y, pf2.x, pf2.w};
    float ax[4] = {af0.x, af0.w, af1.z, af2.y};
    float ay[4] = {af0.y, af1.x, af1.w, af2.z};
    float az[4] = {af0.z, af1.y, af2.x, af2.w};

    float s = 0.f;
#pragma unroll
    for (int r = 0; r < 4; r++) {
        float dx = px[r] - (A00 * ax[r] + A01 * ay[r] + A02 * az[r]) - t0 + TM_EPS;
        float dy = py[r] - (A10 * ax[r] + A11 * ay[r] + A12 * az[r]) - t1 + TM_EPS;
        float dz = pz[r] - (A20 * ax[r] + A21 * ay[r] + A22 * az[r]) - t2 + TM_EPS;
        float d2 = dx * dx + dy * dy + dz * dz;
        s += 1.0f / (1.0f + d2 * inv_d02);
    }
#pragma unroll
    for (int off = 32; off > 0; off >>= 1) s += __shfl_down(s, off);

    __shared__ float red[4];
    int wave = threadIdx.x >> 6, lane = threadIdx.x & 63;
    if (lane == 0) red[wave] = s;
    __syncthreads();
    if (threadIdx.x == 0) {
        float tot = red[0] + red[1] + red[2] + red[3];
        atomicAdd(out, -tot * scale);
    }
}

extern "C" void kernel_launch(void* const* d_in, const int* in_sizes, int n_in,
                              void* d_out, int out_size, void* d_ws, size_t ws_size,
                              hipStream_t stream) {
    const float* pred = (const float*)d_in[0];
    const float* act  = (const float*)d_in[1];
    float* out = (float*)d_out;
    int B = in_sizes[0] / (NRES * 3);

    float* ws   = (float*)d_ws;
    float* sums = ws;                       // B * 16 floats
    float* rot  = ws + (size_t)B * 16;      // B * 12 floats

    hipMemsetAsync(d_out, 0, sizeof(float), stream);

    tm_reduce1<<<B, 256, 0, stream>>>(pred, act, sums);
    tm_kabsch<<<(B + 255) / 256, 256, 0, stream>>>(sums, rot, B);

    double d0 = 1.24 * cbrt((double)NRES - 15.0) - 1.8;
    float inv_d02 = (float)(1.0 / (d0 * d0));
    float scale = 1.0f / ((float)B * (float)NRES);
    tm_score<<<B, 256, 0, stream>>>(pred, act, rot, out, scale, inv_d02);
}

// Round 2
// 120.250 us; speedup vs baseline: 1.0499x; 1.0499x over previous
//
#include <hip/hip_runtime.h>
#include <math.h>

#define NRES 1024
#define TM_EPS 1e-8f

// ---------------- Kernel 1: per-batch sums ----------------
// acc layout: [0..2] sum(pred), [3..5] sum(actual), [6..14] S[i][j] = sum actual_i * pred_j
__global__ void tm_reduce1(const float* __restrict__ pred, const float* __restrict__ act,
                           float* __restrict__ sums) {
    int b = blockIdx.x;
    const float4* p4 = (const float4*)(pred + (size_t)b * NRES * 3);
    const float4* a4 = (const float4*)(act  + (size_t)b * NRES * 3);
    int t = threadIdx.x;

    float4 pf0 = p4[3 * t + 0], pf1 = p4[3 * t + 1], pf2 = p4[3 * t + 2];
    float4 af0 = a4[3 * t + 0], af1 = a4[3 * t + 1], af2 = a4[3 * t + 2];

    float px[4] = {pf0.x, pf0.w, pf1.z, pf2.y};
    float py[4] = {pf0.y, pf1.x, pf1.w, pf2.z};
    float pz[4] = {pf0.z, pf1.y, pf2.x, pf2.w};
    float ax[4] = {af0.x, af0.w, af1.z, af2.y};
    float ay[4] = {af0.y, af1.x, af1.w, af2.z};
    float az[4] = {af0.z, af1.y, af2.x, af2.w};

    float acc[15];
#pragma unroll
    for (int i = 0; i < 15; i++) acc[i] = 0.f;
#pragma unroll
    for (int r = 0; r < 4; r++) {
        acc[0] += px[r]; acc[1] += py[r]; acc[2] += pz[r];
        acc[3] += ax[r]; acc[4] += ay[r]; acc[5] += az[r];
        acc[6]  += ax[r] * px[r]; acc[7]  += ax[r] * py[r]; acc[8]  += ax[r] * pz[r];
        acc[9]  += ay[r] * px[r]; acc[10] += ay[r] * py[r]; acc[11] += ay[r] * pz[r];
        acc[12] += az[r] * px[r]; acc[13] += az[r] * py[r]; acc[14] += az[r] * pz[r];
    }

    // wave(64) shuffle reduction
#pragma unroll
    for (int off = 32; off > 0; off >>= 1) {
#pragma unroll
        for (int i = 0; i < 15; i++) acc[i] += __shfl_down(acc[i], off);
    }
    __shared__ float red[4][15];
    int wave = threadIdx.x >> 6, lane = threadIdx.x & 63;
    if (lane == 0) {
#pragma unroll
        for (int i = 0; i < 15; i++) red[wave][i] = acc[i];
    }
    __syncthreads();
    if (threadIdx.x < 15) {
        int i = threadIdx.x;
        sums[(size_t)b * 16 + i] = red[0][i] + red[1][i] + red[2][i] + red[3][i];
    }
}

// ---------------- Kernel 2: Kabsch rotation via QCP (char-poly Newton + adjugate) ----
__global__ void tm_kabsch(const float* __restrict__ sums, float* __restrict__ rot, int B) {
    int b = blockIdx.x * blockDim.x + threadIdx.x;
    if (b >= B) return;
    const float* s = sums + (size_t)b * 16;
    const double n = (double)NRES;
    double mp[3], mq[3];
#pragma unroll
    for (int i = 0; i < 3; i++) { mp[i] = (double)s[i] / n; mq[i] = (double)s[3 + i] / n; }
    double M[3][3];
#pragma unroll
    for (int i = 0; i < 3; i++)
#pragma unroll
        for (int j = 0; j < 3; j++)
            M[i][j] = (double)s[6 + i * 3 + j] - n * mq[i] * mp[j];

    // Horn's 4x4 key matrix (traceless symmetric). S_ab = sum q_a p_b = M[a][b]
    double Sxx = M[0][0], Sxy = M[0][1], Sxz = M[0][2];
    double Syx = M[1][0], Syy = M[1][1], Syz = M[1][2];
    double Szx = M[2][0], Szy = M[2][1], Szz = M[2][2];
    double K[4][4];
    K[0][0] = Sxx + Syy + Szz; K[0][1] = Syz - Szy;        K[0][2] = Szx - Sxz;         K[0][3] = Sxy - Syx;
    K[1][0] = K[0][1];         K[1][1] = Sxx - Syy - Szz;  K[1][2] = Sxy + Syx;         K[1][3] = Szx + Sxz;
    K[2][0] = K[0][2];         K[2][1] = K[1][2];          K[2][2] = -Sxx + Syy - Szz;  K[2][3] = Syz + Szy;
    K[3][0] = K[0][3];         K[3][1] = K[1][3];          K[3][2] = K[2][3];           K[3][3] = -Sxx - Syy + Szz;

    // power sums p2 = tr(K^2), p3 = tr(K^3), p4 = tr(K^4)
    double K2[4][4];
#pragma unroll
    for (int i = 0; i < 4; i++)
#pragma unroll
        for (int j = 0; j < 4; j++) {
            double acc = 0.0;
#pragma unroll
            for (int k = 0; k < 4; k++) acc += K[i][k] * K[k][j];
            K2[i][j] = acc;
        }
    double p2 = 0.0, p3 = 0.0, p4 = 0.0;
#pragma unroll
    for (int i = 0; i < 4; i++)
#pragma unroll
        for (int j = 0; j < 4; j++) {
            p2 += K[i][j] * K[i][j];
            p3 += K2[i][j] * K[i][j];
            p4 += K2[i][j] * K2[i][j];
        }
    // char poly (trace 0): P(l) = l^4 + e2 l^2 - e3 l + e4
    double e2 = -0.5 * p2;
    double e3 = p3 / 3.0;
    double e4 = (0.5 * p2 * p2 - p4) * 0.25;

    // Newton from above (l0 = sqrt(p2) >= lmax); all roots real -> monotone convergence
    double lam = sqrt(p2);
#pragma unroll
    for (int it = 0; it < 20; it++) {
        double lam2 = lam * lam;
        double P  = lam2 * lam2 + e2 * lam2 - e3 * lam + e4;
        double Pp = 4.0 * lam * lam2 + 2.0 * e2 * lam - e3;
        lam -= P / Pp;
    }

    // eigenvector = max-norm cofactor row of (K - lam I)  (adjugate of rank-3 symmetric)
    double Bm[4][4];
#pragma unroll
    for (int i = 0; i < 4; i++)
#pragma unroll
        for (int j = 0; j < 4; j++) Bm[i][j] = K[i][j] - ((i == j) ? lam : 0.0);

    double cand[4][4];
#pragma unroll
    for (int r = 0; r < 4; r++) {
        int rr[3];
        int k = 0;
#pragma unroll
        for (int i = 0; i < 4; i++) if (i != r) rr[k++] = i;
#pragma unroll
        for (int c = 0; c < 4; c++) {
            int cc[3];
            int m = 0;
#pragma unroll
            for (int j = 0; j < 4; j++) if (j != c) cc[m++] = j;
            double d =
                Bm[rr[0]][cc[0]] * (Bm[rr[1]][cc[1]] * Bm[rr[2]][cc[2]] - Bm[rr[1]][cc[2]] * Bm[rr[2]][cc[1]])
              - Bm[rr[0]][cc[1]] * (Bm[rr[1]][cc[0]] * Bm[rr[2]][cc[2]] - Bm[rr[1]][cc[2]] * Bm[rr[2]][cc[0]])
              + Bm[rr[0]][cc[2]] * (Bm[rr[1]][cc[0]] * Bm[rr[2]][cc[1]] - Bm[rr[1]][cc[1]] * Bm[rr[2]][cc[0]]);
            cand[r][c] = (((r + c) & 1) ? -d : d);
        }
    }
    int bestr = 0;
    double bestn = -1.0;
#pragma unroll
    for (int r = 0; r < 4; r++) {
        double nn = cand[r][0] * cand[r][0] + cand[r][1] * cand[r][1] +
                    cand[r][2] * cand[r][2] + cand[r][3] * cand[r][3];
        if (nn > bestn) { bestn = nn; bestr = r; }
    }
    double w = cand[bestr][0], x = cand[bestr][1], y = cand[bestr][2], z = cand[bestr][3];
    double nrm = sqrt(w * w + x * x + y * y + z * z);
    w /= nrm; x /= nrm; y /= nrm; z /= nrm;

    // rotation A: A * q_col ~= p_col
    double A[3][3];
    A[0][0] = 1.0 - 2.0 * (y * y + z * z); A[0][1] = 2.0 * (x * y - w * z);       A[0][2] = 2.0 * (x * z + w * y);
    A[1][0] = 2.0 * (x * y + w * z);       A[1][1] = 1.0 - 2.0 * (x * x + z * z); A[1][2] = 2.0 * (y * z - w * x);
    A[2][0] = 2.0 * (x * z - w * y);       A[2][1] = 2.0 * (y * z + w * x);       A[2][2] = 1.0 - 2.0 * (x * x + y * y);

    float* o = rot + (size_t)b * 12;
#pragma unroll
    for (int i = 0; i < 3; i++)
#pragma unroll
        for (int j = 0; j < 3; j++) o[i * 3 + j] = (float)A[i][j];
    // t = mu_p - A * mu_q
#pragma unroll
    for (int i = 0; i < 3; i++)
        o[9 + i] = (float)(mp[i] - (A[i][0] * mq[0] + A[i][1] * mq[1] + A[i][2] * mq[2]));
}

// ---------------- Kernel 3: deviations + TM-score sum ----------------
__global__ void tm_score(const float* __restrict__ pred, const float* __restrict__ act,
                         const float* __restrict__ rot, float* __restrict__ out,
                         float scale, float inv_d02) {
    int b = blockIdx.x;
    const float* R = rot + (size_t)b * 12;
    float A00 = R[0], A01 = R[1], A02 = R[2];
    float A10 = R[3], A11 = R[4], A12 = R[5];
    float A20 = R[6], A21 = R[7], A22 = R[8];
    float t0 = R[9], t1 = R[10], t2 = R[11];

    const float4* p4 = (const float4*)(pred + (size_t)b * NRES * 3);
    const float4* a4 = (const float4*)(act  + (size_t)b * NRES * 3);
    int t = threadIdx.x;
    float4 pf0 = p4[3 * t + 0], pf1 = p4[3 * t + 1], pf2 = p4[3 * t + 2];
    float4 af0 = a4[3 * t + 0], af1 = a4[3 * t + 1], af2 = a4[3 * t + 2];

    float px[4] = {pf0.x, pf0.w, pf1.z, pf2.y};
    float py[4] = {pf0.y, pf1.x, pf1.w, pf2.z};
    float pz[4] = {pf0.z, pf1.y, pf2.x, pf2.w};
    float ax[4] = {af0.x, af0.w, af1.z, af2.y};
    float ay[4] = {af0.y, af1.x, af1.w, af2.z};
    float az[4] = {af0.z, af1.y, af2.x, af2.w};

    float s = 0.f;
#pragma unroll
    for (int r = 0; r < 4; r++) {
        float dx = px[r] - (A00 * ax[r] + A01 * ay[r] + A02 * az[r]) - t0 + TM_EPS;
        float dy = py[r] - (A10 * ax[r] + A11 * ay[r] + A12 * az[r]) - t1 + TM_EPS;
        float dz = pz[r] - (A20 * ax[r] + A21 * ay[r] + A22 * az[r]) - t2 + TM_EPS;
        float d2 = dx * dx + dy * dy + dz * dz;
        s += 1.0f / (1.0f + d2 * inv_d02);
    }
#pragma unroll
    for (int off = 32; off > 0; off >>= 1) s += __shfl_down(s, off);

    __shared__ float red[4];
    int wave = threadIdx.x >> 6, lane = threadIdx.x & 63;
    if (lane == 0) red[wave] = s;
    __syncthreads();
    if (threadIdx.x == 0) {
        float tot = red[0] + red[1] + red[2] + red[3];
        atomicAdd(out, -tot * scale);
    }
}

extern "C" void kernel_launch(void* const* d_in, const int* in_sizes, int n_in,
                              void* d_out, int out_size, void* d_ws, size_t ws_size,
                              hipStream_t stream) {
    const float* pred = (const float*)d_in[0];
    const float* act  = (const float*)d_in[1];
    float* out = (float*)d_out;
    int B = in_sizes[0] / (NRES * 3);

    float* ws   = (float*)d_ws;
    float* sums = ws;                       // B * 16 floats
    float* rot  = ws + (size_t)B * 16;      // B * 12 floats

    hipMemsetAsync(d_out, 0, sizeof(float), stream);

    tm_reduce1<<<B, 256, 0, stream>>>(pred, act, sums);
    tm_kabsch<<<(B + 255) / 256, 256, 0, stream>>>(sums, rot, B);

    double d0 = 1.24 * cbrt((double)NRES - 15.0) - 1.8;
    float inv_d02 = (float)(1.0 / (d0 * d0));
    float scale = 1.0f / ((float)B * (float)NRES);
    tm_score<<<B, 256, 0, stream>>>(pred, act, rot, out, scale, inv_d02);
}

// Round 3
// 110.076 us; speedup vs baseline: 1.1469x; 1.0924x over previous
//
#include <hip/hip_runtime.h>
#include <math.h>

#define NRES 1024
#define TM_EPS 1e-8f

// One block per batch: load coords once, stage in LDS, block-reduce the 15
// Kabsch sums, thread 0 solves the QCP quaternion (fp64), broadcast rotation,
// score from LDS. Single HBM pass.
__global__ __launch_bounds__(256, 2) void tm_fused(const float* __restrict__ pred,
                                                   const float* __restrict__ act,
                                                   float* __restrict__ out,
                                                   float scale, float inv_d02) {
    __shared__ float4 sh[6][256];     // 24 KB coord stash (SoA float4: conflict-free)
    __shared__ float red[4][15];
    __shared__ float rotsh[12];

    int b = blockIdx.x;
    int t = threadIdx.x;
    const float4* p4 = (const float4*)(pred + (size_t)b * NRES * 3);
    const float4* a4 = (const float4*)(act  + (size_t)b * NRES * 3);

    float4 pf0 = p4[3 * t + 0], pf1 = p4[3 * t + 1], pf2 = p4[3 * t + 2];
    float4 af0 = a4[3 * t + 0], af1 = a4[3 * t + 1], af2 = a4[3 * t + 2];
    sh[0][t] = pf0; sh[1][t] = pf1; sh[2][t] = pf2;
    sh[3][t] = af0; sh[4][t] = af1; sh[5][t] = af2;

    // ---- phase 1: 15 partial sums from registers ----
    {
        float px[4] = {pf0.x, pf0.w, pf1.z, pf2.y};
        float py[4] = {pf0.y, pf1.x, pf1.w, pf2.z};
        float pz[4] = {pf0.z, pf1.y, pf2.x, pf2.w};
        float ax[4] = {af0.x, af0.w, af1.z, af2.y};
        float ay[4] = {af0.y, af1.x, af1.w, af2.z};
        float az[4] = {af0.z, af1.y, af2.x, af2.w};

        float acc[15];
#pragma unroll
        for (int i = 0; i < 15; i++) acc[i] = 0.f;
#pragma unroll
        for (int r = 0; r < 4; r++) {
            acc[0] += px[r]; acc[1] += py[r]; acc[2] += pz[r];
            acc[3] += ax[r]; acc[4] += ay[r]; acc[5] += az[r];
            acc[6]  += ax[r] * px[r]; acc[7]  += ax[r] * py[r]; acc[8]  += ax[r] * pz[r];
            acc[9]  += ay[r] * px[r]; acc[10] += ay[r] * py[r]; acc[11] += ay[r] * pz[r];
            acc[12] += az[r] * px[r]; acc[13] += az[r] * py[r]; acc[14] += az[r] * pz[r];
        }
#pragma unroll
        for (int off = 32; off > 0; off >>= 1) {
#pragma unroll
            for (int i = 0; i < 15; i++) acc[i] += __shfl_down(acc[i], off);
        }
        int wave = t >> 6, lane = t & 63;
        if (lane == 0) {
#pragma unroll
            for (int i = 0; i < 15; i++) red[wave][i] = acc[i];
        }
    }
    __syncthreads();

    // ---- phase 2 (thread 0): QCP solve ----
    if (t == 0) {
        float s[15];
#pragma unroll
        for (int i = 0; i < 15; i++) s[i] = red[0][i] + red[1][i] + red[2][i] + red[3][i];

        const double n = (double)NRES;
        double mp[3], mq[3];
#pragma unroll
        for (int i = 0; i < 3; i++) { mp[i] = (double)s[i] / n; mq[i] = (double)s[3 + i] / n; }
        double M[3][3];
#pragma unroll
        for (int i = 0; i < 3; i++)
#pragma unroll
            for (int j = 0; j < 3; j++)
                M[i][j] = (double)s[6 + i * 3 + j] - n * mq[i] * mp[j];

        double Sxx = M[0][0], Sxy = M[0][1], Sxz = M[0][2];
        double Syx = M[1][0], Syy = M[1][1], Syz = M[1][2];
        double Szx = M[2][0], Szy = M[2][1], Szz = M[2][2];
        double K[4][4];
        K[0][0] = Sxx + Syy + Szz; K[0][1] = Syz - Szy;        K[0][2] = Szx - Sxz;         K[0][3] = Sxy - Syx;
        K[1][0] = K[0][1];         K[1][1] = Sxx - Syy - Szz;  K[1][2] = Sxy + Syx;         K[1][3] = Szx + Sxz;
        K[2][0] = K[0][2];         K[2][1] = K[1][2];          K[2][2] = -Sxx + Syy - Szz;  K[2][3] = Syz + Szy;
        K[3][0] = K[0][3];         K[3][1] = K[1][3];          K[3][2] = K[2][3];           K[3][3] = -Sxx - Syy + Szz;

        double K2[4][4];
#pragma unroll
        for (int i = 0; i < 4; i++)
#pragma unroll
            for (int j = 0; j < 4; j++) {
                double acc = 0.0;
#pragma unroll
                for (int k = 0; k < 4; k++) acc += K[i][k] * K[k][j];
                K2[i][j] = acc;
            }
        double p2 = 0.0, p3 = 0.0, p4s = 0.0;
#pragma unroll
        for (int i = 0; i < 4; i++)
#pragma unroll
            for (int j = 0; j < 4; j++) {
                p2 += K[i][j] * K[i][j];
                p3 += K2[i][j] * K[i][j];
                p4s += K2[i][j] * K2[i][j];
            }
        double e2 = -0.5 * p2;
        double e3 = p3 / 3.0;
        double e4 = (0.5 * p2 * p2 - p4s) * 0.25;

        double lam = sqrt(p2);
#pragma unroll
        for (int it = 0; it < 14; it++) {
            double lam2 = lam * lam;
            double P  = lam2 * lam2 + e2 * lam2 - e3 * lam + e4;
            double Pp = 4.0 * lam * lam2 + 2.0 * e2 * lam - e3;
            lam -= P / Pp;
        }

        double Bm[4][4];
#pragma unroll
        for (int i = 0; i < 4; i++)
#pragma unroll
            for (int j = 0; j < 4; j++) Bm[i][j] = K[i][j] - ((i == j) ? lam : 0.0);

        double cand[4][4];
#pragma unroll
        for (int r = 0; r < 4; r++) {
            int rr[3]; int k = 0;
#pragma unroll
            for (int i = 0; i < 4; i++) if (i != r) rr[k++] = i;
#pragma unroll
            for (int c = 0; c < 4; c++) {
                int cc[3]; int m = 0;
#pragma unroll
                for (int j = 0; j < 4; j++) if (j != c) cc[m++] = j;
                double d =
                    Bm[rr[0]][cc[0]] * (Bm[rr[1]][cc[1]] * Bm[rr[2]][cc[2]] - Bm[rr[1]][cc[2]] * Bm[rr[2]][cc[1]])
                  - Bm[rr[0]][cc[1]] * (Bm[rr[1]][cc[0]] * Bm[rr[2]][cc[2]] - Bm[rr[1]][cc[2]] * Bm[rr[2]][cc[0]])
                  + Bm[rr[0]][cc[2]] * (Bm[rr[1]][cc[0]] * Bm[rr[2]][cc[1]] - Bm[rr[1]][cc[1]] * Bm[rr[2]][cc[0]]);
                cand[r][c] = (((r + c) & 1) ? -d : d);
            }
        }
        int bestr = 0;
        double bestn = -1.0;
#pragma unroll
        for (int r = 0; r < 4; r++) {
            double nn = cand[r][0] * cand[r][0] + cand[r][1] * cand[r][1] +
                        cand[r][2] * cand[r][2] + cand[r][3] * cand[r][3];
            if (nn > bestn) { bestn = nn; bestr = r; }
        }
        double w = cand[bestr][0], x = cand[bestr][1], y = cand[bestr][2], z = cand[bestr][3];
        double nrm = sqrt(w * w + x * x + y * y + z * z);
        w /= nrm; x /= nrm; y /= nrm; z /= nrm;

        double A[3][3];
        A[0][0] = 1.0 - 2.0 * (y * y + z * z); A[0][1] = 2.0 * (x * y - w * z);       A[0][2] = 2.0 * (x * z + w * y);
        A[1][0] = 2.0 * (x * y + w * z);       A[1][1] = 1.0 - 2.0 * (x * x + z * z); A[1][2] = 2.0 * (y * z - w * x);
        A[2][0] = 2.0 * (x * z - w * y);       A[2][1] = 2.0 * (y * z + w * x);       A[2][2] = 1.0 - 2.0 * (x * x + y * y);

#pragma unroll
        for (int i = 0; i < 3; i++)
#pragma unroll
            for (int j = 0; j < 3; j++) rotsh[i * 3 + j] = (float)A[i][j];
#pragma unroll
        for (int i = 0; i < 3; i++)
            rotsh[9 + i] = (float)(mp[i] - (A[i][0] * mq[0] + A[i][1] * mq[1] + A[i][2] * mq[2]));
    }
    __syncthreads();

    // ---- phase 3: score from LDS ----
    float A00 = rotsh[0], A01 = rotsh[1], A02 = rotsh[2];
    float A10 = rotsh[3], A11 = rotsh[4], A12 = rotsh[5];
    float A20 = rotsh[6], A21 = rotsh[7], A22 = rotsh[8];
    float t0 = rotsh[9], t1 = rotsh[10], t2 = rotsh[11];

    float4 qf0 = sh[0][t], qf1 = sh[1][t], qf2 = sh[2][t];
    float4 bf0 = sh[3][t], bf1 = sh[4][t], bf2 = sh[5][t];

    float px[4] = {qf0.x, qf0.w, qf1.z, qf2.y};
    float py[4] = {qf0.y, qf1.x, qf1.w, qf2.z};
    float pz[4] = {qf0.z, qf1.y, qf2.x, qf2.w};
    float ax[4] = {bf0.x, bf0.w, bf1.z, bf2.y};
    float ay[4] = {bf0.y, bf1.x, bf1.w, bf2.z};
    float az[4] = {bf0.z, bf1.y, bf2.x, bf2.w};

    float sc = 0.f;
#pragma unroll
    for (int r = 0; r < 4; r++) {
        float dx = px[r] - (A00 * ax[r] + A01 * ay[r] + A02 * az[r]) - t0 + TM_EPS;
        float dy = py[r] - (A10 * ax[r] + A11 * ay[r] + A12 * az[r]) - t1 + TM_EPS;
        float dz = pz[r] - (A20 * ax[r] + A21 * ay[r] + A22 * az[r]) - t2 + TM_EPS;
        float d2 = dx * dx + dy * dy + dz * dz;
        sc += 1.0f / (1.0f + d2 * inv_d02);
    }
#pragma unroll
    for (int off = 32; off > 0; off >>= 1) sc += __shfl_down(sc, off);

    __shared__ float red2[4];
    int wave = t >> 6, lane = t & 63;
    if (lane == 0) red2[wave] = sc;
    __syncthreads();
    if (t == 0) {
        float tot = red2[0] + red2[1] + red2[2] + red2[3];
        atomicAdd(out, -tot * scale);
    }
}

extern "C" void kernel_launch(void* const* d_in, const int* in_sizes, int n_in,
                              void* d_out, int out_size, void* d_ws, size_t ws_size,
                              hipStream_t stream) {
    const float* pred = (const float*)d_in[0];
    const float* act  = (const float*)d_in[1];
    float* out = (float*)d_out;
    int B = in_sizes[0] / (NRES * 3);

    hipMemsetAsync(d_out, 0, sizeof(float), stream);

    double d0 = 1.24 * cbrt((double)NRES - 15.0) - 1.8;
    float inv_d02 = (float)(1.0 / (d0 * d0));
    float scale = 1.0f / ((float)B * (float)NRES);
    tm_fused<<<B, 256, 0, stream>>>(pred, act, out, scale, inv_d02);
}

// Round 4
// 106.738 us; speedup vs baseline: 1.1828x; 1.0313x over previous
//
#include <hip/hip_runtime.h>
#include <math.h>

#define NRES 1024
#define TM_EPS 1e-8f

// One block per batch, single HBM pass. Coords live in registers across the
// whole kernel (no LDS stash). Block-reduce 15 Kabsch sums -> thread 0 runs a
// fp32 QCP (char-poly Newton + adjugate) solve -> broadcast A,t -> score.
// fp32 solve error ~1e-7 in the loss vs 2e-2 threshold (see round journal).
__global__ __launch_bounds__(256, 4) void tm_fused(const float* __restrict__ pred,
                                                   const float* __restrict__ act,
                                                   float* __restrict__ out,
                                                   float scale, float inv_d02) {
    __shared__ float red[4][15];
    __shared__ float rotsh[12];
    __shared__ float red2[4];

    int b = blockIdx.x;
    int t = threadIdx.x;
    const float4* p4 = (const float4*)(pred + (size_t)b * NRES * 3);
    const float4* a4 = (const float4*)(act  + (size_t)b * NRES * 3);

    float4 pf0 = p4[3 * t + 0], pf1 = p4[3 * t + 1], pf2 = p4[3 * t + 2];
    float4 af0 = a4[3 * t + 0], af1 = a4[3 * t + 1], af2 = a4[3 * t + 2];

    float px[4] = {pf0.x, pf0.w, pf1.z, pf2.y};
    float py[4] = {pf0.y, pf1.x, pf1.w, pf2.z};
    float pz[4] = {pf0.z, pf1.y, pf2.x, pf2.w};
    float ax[4] = {af0.x, af0.w, af1.z, af2.y};
    float ay[4] = {af0.y, af1.x, af1.w, af2.z};
    float az[4] = {af0.z, af1.y, af2.x, af2.w};

    // ---- phase 1: 15 partial sums ----
    {
        float acc[15];
#pragma unroll
        for (int i = 0; i < 15; i++) acc[i] = 0.f;
#pragma unroll
        for (int r = 0; r < 4; r++) {
            acc[0] += px[r]; acc[1] += py[r]; acc[2] += pz[r];
            acc[3] += ax[r]; acc[4] += ay[r]; acc[5] += az[r];
            acc[6]  += ax[r] * px[r]; acc[7]  += ax[r] * py[r]; acc[8]  += ax[r] * pz[r];
            acc[9]  += ay[r] * px[r]; acc[10] += ay[r] * py[r]; acc[11] += ay[r] * pz[r];
            acc[12] += az[r] * px[r]; acc[13] += az[r] * py[r]; acc[14] += az[r] * pz[r];
        }
#pragma unroll
        for (int off = 32; off > 0; off >>= 1) {
#pragma unroll
            for (int i = 0; i < 15; i++) acc[i] += __shfl_down(acc[i], off);
        }
        int wave = t >> 6, lane = t & 63;
        if (lane == 0) {
#pragma unroll
            for (int i = 0; i < 15; i++) red[wave][i] = acc[i];
        }
    }
    __syncthreads();

    // ---- phase 2 (thread 0): fp32 QCP solve ----
    if (t == 0) {
        float s[15];
#pragma unroll
        for (int i = 0; i < 15; i++) s[i] = red[0][i] + red[1][i] + red[2][i] + red[3][i];

        const float n = (float)NRES;
        float mp[3], mq[3];
#pragma unroll
        for (int i = 0; i < 3; i++) { mp[i] = s[i] / n; mq[i] = s[3 + i] / n; }
        float M[3][3];
#pragma unroll
        for (int i = 0; i < 3; i++)
#pragma unroll
            for (int j = 0; j < 3; j++)
                M[i][j] = s[6 + i * 3 + j] - n * mq[i] * mp[j];

        float Sxx = M[0][0], Sxy = M[0][1], Sxz = M[0][2];
        float Syx = M[1][0], Syy = M[1][1], Syz = M[1][2];
        float Szx = M[2][0], Szy = M[2][1], Szz = M[2][2];
        float K[4][4];
        K[0][0] = Sxx + Syy + Szz; K[0][1] = Syz - Szy;        K[0][2] = Szx - Sxz;         K[0][3] = Sxy - Syx;
        K[1][0] = K[0][1];         K[1][1] = Sxx - Syy - Szz;  K[1][2] = Sxy + Syx;         K[1][3] = Szx + Sxz;
        K[2][0] = K[0][2];         K[2][1] = K[1][2];          K[2][2] = -Sxx + Syy - Szz;  K[2][3] = Syz + Szy;
        K[3][0] = K[0][3];         K[3][1] = K[1][3];          K[3][2] = K[2][3];           K[3][3] = -Sxx - Syy + Szz;

        float K2[4][4];
#pragma unroll
        for (int i = 0; i < 4; i++)
#pragma unroll
            for (int j = 0; j < 4; j++) {
                float acc = 0.f;
#pragma unroll
                for (int k = 0; k < 4; k++) acc += K[i][k] * K[k][j];
                K2[i][j] = acc;
            }
        float p2 = 0.f, p3 = 0.f, p4s = 0.f;
#pragma unroll
        for (int i = 0; i < 4; i++)
#pragma unroll
            for (int j = 0; j < 4; j++) {
                p2 += K[i][j] * K[i][j];
                p3 += K2[i][j] * K[i][j];
                p4s += K2[i][j] * K2[i][j];
            }
        float e2 = -0.5f * p2;
        float e3 = p3 * (1.f / 3.f);
        float e4 = (0.5f * p2 * p2 - p4s) * 0.25f;

        float lam = sqrtf(p2);
#pragma unroll
        for (int it = 0; it < 12; it++) {
            float lam2 = lam * lam;
            float P  = lam2 * lam2 + e2 * lam2 - e3 * lam + e4;
            float Pp = 4.f * lam * lam2 + 2.f * e2 * lam - e3;
            lam -= P / Pp;
        }

        float Bm[4][4];
#pragma unroll
        for (int i = 0; i < 4; i++)
#pragma unroll
            for (int j = 0; j < 4; j++) Bm[i][j] = K[i][j] - ((i == j) ? lam : 0.f);

        float cand[4][4];
#pragma unroll
        for (int r = 0; r < 4; r++) {
            int rr[3]; int k = 0;
#pragma unroll
            for (int i = 0; i < 4; i++) if (i != r) rr[k++] = i;
#pragma unroll
            for (int c = 0; c < 4; c++) {
                int cc[3]; int m = 0;
#pragma unroll
                for (int j = 0; j < 4; j++) if (j != c) cc[m++] = j;
                float d =
                    Bm[rr[0]][cc[0]] * (Bm[rr[1]][cc[1]] * Bm[rr[2]][cc[2]] - Bm[rr[1]][cc[2]] * Bm[rr[2]][cc[1]])
                  - Bm[rr[0]][cc[1]] * (Bm[rr[1]][cc[0]] * Bm[rr[2]][cc[2]] - Bm[rr[1]][cc[2]] * Bm[rr[2]][cc[0]])
                  + Bm[rr[0]][cc[2]] * (Bm[rr[1]][cc[0]] * Bm[rr[2]][cc[1]] - Bm[rr[1]][cc[1]] * Bm[rr[2]][cc[0]]);
                cand[r][c] = (((r + c) & 1) ? -d : d);
            }
        }
        int bestr = 0;
        float bestn = -1.f;
#pragma unroll
        for (int r = 0; r < 4; r++) {
            float nn = cand[r][0] * cand[r][0] + cand[r][1] * cand[r][1] +
                       cand[r][2] * cand[r][2] + cand[r][3] * cand[r][3];
            if (nn > bestn) { bestn = nn; bestr = r; }
        }
        float w = cand[bestr][0], x = cand[bestr][1], y = cand[bestr][2], z = cand[bestr][3];
        float inrm = 1.f / sqrtf(w * w + x * x + y * y + z * z);
        w *= inrm; x *= inrm; y *= inrm; z *= inrm;

        float A[3][3];
        A[0][0] = 1.f - 2.f * (y * y + z * z); A[0][1] = 2.f * (x * y - w * z);       A[0][2] = 2.f * (x * z + w * y);
        A[1][0] = 2.f * (x * y + w * z);       A[1][1] = 1.f - 2.f * (x * x + z * z); A[1][2] = 2.f * (y * z - w * x);
        A[2][0] = 2.f * (x * z - w * y);       A[2][1] = 2.f * (y * z + w * x);       A[2][2] = 1.f - 2.f * (x * x + y * y);

#pragma unroll
        for (int i = 0; i < 3; i++)
#pragma unroll
            for (int j = 0; j < 3; j++) rotsh[i * 3 + j] = A[i][j];
#pragma unroll
        for (int i = 0; i < 3; i++)
            rotsh[9 + i] = mp[i] - (A[i][0] * mq[0] + A[i][1] * mq[1] + A[i][2] * mq[2]);
    }
    __syncthreads();

    // ---- phase 3: score from registers ----
    float A00 = rotsh[0], A01 = rotsh[1], A02 = rotsh[2];
    float A10 = rotsh[3], A11 = rotsh[4], A12 = rotsh[5];
    float A20 = rotsh[6], A21 = rotsh[7], A22 = rotsh[8];
    float t0 = rotsh[9], t1 = rotsh[10], t2 = rotsh[11];

    float sc = 0.f;
#pragma unroll
    for (int r = 0; r < 4; r++) {
        float dx = px[r] - (A00 * ax[r] + A01 * ay[r] + A02 * az[r]) - t0 + TM_EPS;
        float dy = py[r] - (A10 * ax[r] + A11 * ay[r] + A12 * az[r]) - t1 + TM_EPS;
        float dz = pz[r] - (A20 * ax[r] + A21 * ay[r] + A22 * az[r]) - t2 + TM_EPS;
        float d2 = dx * dx + dy * dy + dz * dz;
        sc += 1.0f / (1.0f + d2 * inv_d02);
    }
#pragma unroll
    for (int off = 32; off > 0; off >>= 1) sc += __shfl_down(sc, off);

    int wave = t >> 6, lane = t & 63;
    if (lane == 0) red2[wave] = sc;
    __syncthreads();
    if (t == 0) {
        float tot = red2[0] + red2[1] + red2[2] + red2[3];
        atomicAdd(out, -tot * scale);
    }
}

extern "C" void kernel_launch(void* const* d_in, const int* in_sizes, int n_in,
                              void* d_out, int out_size, void* d_ws, size_t ws_size,
                              hipStream_t stream) {
    const float* pred = (const float*)d_in[0];
    const float* act  = (const float*)d_in[1];
    float* out = (float*)d_out;
    int B = in_sizes[0] / (NRES * 3);

    hipMemsetAsync(d_out, 0, sizeof(float), stream);

    double d0 = 1.24 * cbrt((double)NRES - 15.0) - 1.8;
    float inv_d02 = (float)(1.0 / (d0 * d0));
    float scale = 1.0f / ((float)B * (float)NRES);
    tm_fused<<<B, 256, 0, stream>>>(pred, act, out, scale, inv_d02);
}